// Round 7
// baseline (10818.073 us; speedup 1.0000x reference)
//
#include <hip/hip_runtime.h>
#include <hip/hip_bf16.h>

#define SEQ 4096
#define EMB 1024
#define HID 2048
#define G4  8192
#define NL  256

typedef __attribute__((ext_vector_type(8))) short bf16x8;
typedef __attribute__((ext_vector_type(4))) float f32x4;

static __device__ __forceinline__ unsigned short f2bf(float f) {
    unsigned int x = __builtin_bit_cast(unsigned int, f);
    return (unsigned short)((x + 0x7FFFu + ((x >> 16) & 1u)) >> 16);
}
static __device__ __forceinline__ float bf2f(unsigned short u) {
    return __builtin_bit_cast(float, ((unsigned int)u) << 16);
}
static __device__ __forceinline__ unsigned long long aload(const unsigned long long* p) {
    return __hip_atomic_load(p, __ATOMIC_RELAXED, __HIP_MEMORY_SCOPE_AGENT);
}
static __device__ __forceinline__ float fsigm(float x) {
    return 1.f / (1.f + __expf(-x));
}
static __device__ __forceinline__ float ftanh(float x) {
    return 1.f - 2.f / (__expf(2.f * x) + 1.f);
}

// ---------------- fp32 -> bf16 convert ----------------
__global__ __launch_bounds__(256) void k_f2b(const float* __restrict__ in,
                                             unsigned short* __restrict__ out, int n) {
    int i = (blockIdx.x * 256 + threadIdx.x) * 4;
    if (i < n) {
        float4 v = *(const float4*)&in[i];
        ushort4 u;
        u.x = f2bf(v.x); u.y = f2bf(v.y); u.z = f2bf(v.z); u.w = f2bf(v.w);
        *(ushort4*)&out[i] = u;
    }
}

// ---------------- embedding gather + cast ----------------
__global__ __launch_bounds__(256) void k_emb(const int* __restrict__ ids,
                                             const float* __restrict__ W_emb,
                                             unsigned short* __restrict__ out) {
    int t = blockIdx.x;
    int e0 = threadIdx.x * 4;
    const float4 v = *(const float4*)&W_emb[(size_t)ids[t] * EMB + e0];
    ushort4 u;
    u.x = f2bf(v.x); u.y = f2bf(v.y); u.z = f2bf(v.z); u.w = f2bf(v.w);
    *(ushort4*)&out[(size_t)t * EMB + e0] = u;
}

// ---------------- bf16 MFMA GEMM:  C[M,N] = A[M,K] * B[N,K]^T + bias ----------------
#define BM 128
#define BN 128
#define BK 32
__global__ __launch_bounds__(256) void k_gemm_bt(
    const unsigned short* __restrict__ A, const unsigned short* __restrict__ B,
    const float* __restrict__ bias1, const float* __restrict__ bias2,
    float* __restrict__ Cf, unsigned short* __restrict__ Cb,
    int M, int N, int K)
{
    __shared__ unsigned short As[BM * BK];
    __shared__ unsigned short Bs[BN * BK];
    const int bm = blockIdx.x * BM;
    const int bn = blockIdx.y * BN;
    const int tid = threadIdx.x;
    const int wave = tid >> 6, lane = tid & 63;
    const int wm = (wave & 1) * 64, wn = (wave >> 1) * 64;
    const int row16 = lane & 15, quad = lane >> 4;

    f32x4 acc[4][4];
#pragma unroll
    for (int i = 0; i < 4; ++i)
#pragma unroll
        for (int j = 0; j < 4; ++j) acc[i][j] = (f32x4){0.f, 0.f, 0.f, 0.f};

    for (int k0 = 0; k0 < K; k0 += BK) {
        __syncthreads();
#pragma unroll
        for (int s = 0; s < 2; ++s) {
            int c = tid + s * 256;
            int r = c >> 2, col = (c & 3) * 8;
            *(uint4*)&As[r * BK + col] = *(const uint4*)&A[(size_t)(bm + r) * K + k0 + col];
            *(uint4*)&Bs[r * BK + col] = *(const uint4*)&B[(size_t)(bn + r) * K + k0 + col];
        }
        __syncthreads();
        bf16x8 af[4], bfr[4];
#pragma unroll
        for (int i = 0; i < 4; ++i) {
            af[i]  = *(const bf16x8*)&As[(wm + i * 16 + row16) * BK + quad * 8];
            bfr[i] = *(const bf16x8*)&Bs[(wn + i * 16 + row16) * BK + quad * 8];
        }
#pragma unroll
        for (int i = 0; i < 4; ++i)
#pragma unroll
            for (int j = 0; j < 4; ++j)
                acc[i][j] = __builtin_amdgcn_mfma_f32_16x16x32_bf16(af[i], bfr[j], acc[i][j], 0, 0, 0);
    }

#pragma unroll
    for (int j = 0; j < 4; ++j) {
        int col = bn + wn + j * 16 + row16;
        float bsum = (bias1 ? bias1[col] : 0.f) + (bias2 ? bias2[col] : 0.f);
#pragma unroll
        for (int i = 0; i < 4; ++i) {
#pragma unroll
            for (int r = 0; r < 4; ++r) {
                int row = bm + wm + i * 16 + quad * 4 + r;
                float v = acc[i][j][r] + bsum;
                if (Cf) Cf[(size_t)row * N + col] = v;
                else    Cb[(size_t)row * N + col] = f2bf(v);
            }
        }
    }
}

// ---------------- persistent LSTM recurrence (register-direct MFMA) ----------------
// 128 blocks x 1024 threads, 1 block/CU. Block b owns h[b*16..b*16+16) and the 64
// gate rows {q*2048 + b*16 + j}. Wave w owns k-cols [w*128,w*128+128): 16 A-frags
// (4 gates x 4 chunks) in 64 VGPRs. Rationale: aggregate poll bandwidth is the
// floor (r4/r6 evidence) and poll bytes/CU are irreducible, so HALVE the CUs
// (128 pollers not 256) and cut poll frequency (pre-sleep + sleep(2) spin).
// h exchange: 8-way replicated mailbox of tagged 8B words (tag32 | 2xbf16),
// relaxed agent atomics, no fences. One barrier/step, single-wave epilogue.
#define LSTM_LDS 90112
__global__ __launch_bounds__(1024, 1) void k_lstm(
    const unsigned short* __restrict__ Whhb, // [8192,2048] bf16
    const unsigned short* __restrict__ xg,   // [4096,8192] bf16
    const float* __restrict__ h0, const float* __restrict__ c0,
    unsigned short* __restrict__ hsb,        // [4096,2048] bf16
    float* __restrict__ outHC,               // d_out + SEQ*NL : [hL(2048), cL(2048)]
    unsigned long long* __restrict__ hcomm)  // [2][8 replicas][1024] tagged words
{
    extern __shared__ char smem[];
    float* LDSp = (float*)smem;              // 2 buffers x [64 rows][stride 17]

    const int b = blockIdx.x, tid = threadIdx.x;
    const int wave = tid >> 6, lane = tid & 63;
    const int sub = lane & 15, quad = lane >> 4;

    // A-fragments: afr[q][c] = W_hh row (q*2048 + b*16 + sub), k-cols
    // wave*128 + c*32 + quad*8 .. +8   (A[m=sub][k=quad*8+e] layout)
    bf16x8 afr[4][4];
#pragma unroll
    for (int q = 0; q < 4; ++q) {
        const unsigned short* wsrc =
            Whhb + ((size_t)(q * HID + b * 16 + sub)) * HID + wave * 128 + quad * 8;
#pragma unroll
        for (int c = 0; c < 4; ++c)
            afr[q][c] = *(const bf16x8*)(wsrc + c * 32);
    }

    float creg = 0.f;
    if (tid < 16) creg = c0[b * 16 + tid];

    for (int t = 0; t < SEQ; ++t) {
        // wave0 activation lanes prefetch their 4 x-gate values (overlaps poll)
        float xq0 = 0.f, xq1 = 0.f, xq2 = 0.f, xq3 = 0.f;
        if (wave == 0 && lane < 16) {
            const unsigned short* xr = xg + (size_t)t * G4 + b * 16 + lane;
            xq0 = bf2f(xr[0]);
            xq1 = bf2f(xr[2048]);
            xq2 = bf2f(xr[4096]);
            xq3 = bf2f(xr[6144]);
        }

        f32x4 acc[4];
#pragma unroll
        for (int q = 0; q < 4; ++q) acc[q] = (f32x4){0.f, 0.f, 0.f, 0.f};

        if (t == 0) {
#pragma unroll
            for (int c = 0; c < 4; ++c) {
                const float* hp = h0 + wave * 128 + c * 32 + quad * 8;
                float4 va = *(const float4*)hp;
                float4 vb = *(const float4*)(hp + 4);
                uint4 d;
                d.x = (unsigned)f2bf(va.x) | ((unsigned)f2bf(va.y) << 16);
                d.y = (unsigned)f2bf(va.z) | ((unsigned)f2bf(va.w) << 16);
                d.z = (unsigned)f2bf(vb.x) | ((unsigned)f2bf(vb.y) << 16);
                d.w = (unsigned)f2bf(vb.z) | ((unsigned)f2bf(vb.w) << 16);
                bf16x8 hf = __builtin_bit_cast(bf16x8, d);
#pragma unroll
                for (int q = 0; q < 4; ++q)
                    acc[q] = __builtin_amdgcn_mfma_f32_16x16x32_bf16(afr[q][c], hf, acc[q], 0, 0, 0);
            }
        } else {
            // lane L polls its own word in THIS block's replica (b&7).
            // Pre-sleep: nothing can arrive before producer epilogue + RTT, and
            // idle polling steals memory-pipe slots from the publish stores.
            const unsigned long long* src =
                hcomm + (size_t)((t - 1) & 1) * 8192 + (size_t)(b & 7) * 1024 + wave * 64;
            const unsigned tag = (unsigned)t;
            if (wave != 0) __builtin_amdgcn_s_sleep(10);
            unsigned long long x;
            for (;;) {
                x = aload(&src[lane]);
                if ((unsigned)(x >> 32) == tag) break;
                __builtin_amdgcn_s_sleep(2);
            }
            int myd = (int)(unsigned)x;
#pragma unroll
            for (int c = 0; c < 4; ++c) {
                const int sl = c * 16 + quad * 4;
                uint4 d;
                d.x = (unsigned)__shfl(myd, sl + 0);
                d.y = (unsigned)__shfl(myd, sl + 1);
                d.z = (unsigned)__shfl(myd, sl + 2);
                d.w = (unsigned)__shfl(myd, sl + 3);
                bf16x8 hf = __builtin_bit_cast(bf16x8, d);
#pragma unroll
                for (int q = 0; q < 4; ++q)
                    acc[q] = __builtin_amdgcn_mfma_f32_16x16x32_bf16(afr[q][c], hf, acc[q], 0, 0, 0);
            }
        }

        // partials -> double-buffered LDS, ONE barrier per step.
        float* P = LDSp + (t & 1) * 1100;
        if (sub == 0) {
#pragma unroll
            for (int q = 0; q < 4; ++q)
#pragma unroll
                for (int r = 0; r < 4; ++r)
                    P[(q * 16 + quad * 4 + r) * 17 + wave] = acc[q][r];
        }
        __syncthreads();

        if (wave == 0) {
            // lane L (<64) reduces gate row L: q=L>>4, j=L&15
            const float* rp = P + lane * 17;
            float g = 0.f;
#pragma unroll
            for (int i = 0; i < 16; ++i) g += rp[i];
            float gF = __shfl(g, lane + 16);
            float gG = __shfl(g, lane + 32);
            float gO = __shfl(g, lane + 48);
            unsigned hv = 0;
            float cn = 0.f, hn = 0.f;
            if (lane < 16) {
                float gi = g  + xq0;
                float gf = gF + xq1;
                float gg = gG + xq2;
                float go = gO + xq3;
                float i_ = fsigm(gi);
                float f_ = fsigm(gf);
                float g_ = ftanh(gg);
                float o_ = fsigm(go);
                cn = f_ * creg + i_ * g_;
                hn = o_ * ftanh(cn);
                creg = cn;
                hv = (unsigned)f2bf(hn);
            }
            // publish: lane L -> replica L>>3, word j8=L&7 (pair h[2j8],h[2j8+1])
            {
                int j8 = lane & 7;
                unsigned lo = (unsigned)__shfl((int)hv, 2 * j8);
                unsigned hi = (unsigned)__shfl((int)hv, 2 * j8 + 1);
                unsigned long long wrd =
                    (((unsigned long long)(unsigned)(t + 1)) << 32)
                    | (unsigned long long)(lo | (hi << 16));
                __hip_atomic_store(
                    &hcomm[(size_t)(t & 1) * 8192 + (size_t)(lane >> 3) * 1024 + b * 8 + j8],
                    wrd, __ATOMIC_RELAXED, __HIP_MEMORY_SCOPE_AGENT);
            }
            if (lane < 16) {
                hsb[(size_t)t * HID + b * 16 + lane] = (unsigned short)hv;
                if (t == SEQ - 1) {
                    outHC[b * 16 + lane] = hn;
                    outHC[HID + b * 16 + lane] = cn;
                }
            }
        }
    }
}

// ---------------- relu + log_softmax over rows of 256 ----------------
__global__ __launch_bounds__(256) void k_softmax(const float* __restrict__ logits,
                                                 float* __restrict__ out) {
    int row = blockIdx.x * 4 + (threadIdx.x >> 6);
    int lane = threadIdx.x & 63;
    const float* Lr = logits + (size_t)row * NL;
    float4 v = *(const float4*)&Lr[lane * 4];
    v.x = fmaxf(v.x, 0.f); v.y = fmaxf(v.y, 0.f);
    v.z = fmaxf(v.z, 0.f); v.w = fmaxf(v.w, 0.f);
    float m = fmaxf(fmaxf(v.x, v.y), fmaxf(v.z, v.w));
#pragma unroll
    for (int off = 32; off > 0; off >>= 1) m = fmaxf(m, __shfl_xor(m, off));
    float e = __expf(v.x - m) + __expf(v.y - m) + __expf(v.z - m) + __expf(v.w - m);
#pragma unroll
    for (int off = 32; off > 0; off >>= 1) e += __shfl_xor(e, off);
    float ls = __logf(e) + m;
    float4 o;
    o.x = v.x - ls; o.y = v.y - ls; o.z = v.z - ls; o.w = v.w - ls;
    *(float4*)&out[(size_t)row * NL + lane * 4] = o;
}

extern "C" void kernel_launch(void* const* d_in, const int* in_sizes, int n_in,
                              void* d_out, int out_size, void* d_ws, size_t ws_size,
                              hipStream_t stream) {
    const int*   ids   = (const int*)d_in[0];
    const float* h0    = (const float*)d_in[1];
    const float* c0    = (const float*)d_in[2];
    const float* W_emb = (const float*)d_in[3];
    const float* W_ih  = (const float*)d_in[4];
    const float* W_hh  = (const float*)d_in[5];
    const float* b_ih  = (const float*)d_in[6];
    const float* b_hh  = (const float*)d_in[7];
    const float* W_out = (const float*)d_in[8];
    const float* b_out = (const float*)d_in[9];
    float* out = (float*)d_out;

    char* ws = (char*)d_ws;
    unsigned short* xg    = (unsigned short*)(ws);                 // 64MB  [4096,8192] bf16
    unsigned short* hsb   = (unsigned short*)(ws + 67108864);      // 16MB  [4096,2048] bf16
    unsigned short* Wihb  = (unsigned short*)(ws + 83886080);      // 16MB
    unsigned short* embb  = (unsigned short*)(ws + 100663296);     // 8MB
    unsigned short* Woutb = (unsigned short*)(ws + 109051904);     // 1MB
    float*          logit = (float*)(ws + 110100480);              // 4MB
    unsigned short* Whhb  = (unsigned short*)(ws + 114294784);     // 32MB [8192,2048] bf16
    unsigned long long* hcomm = (unsigned long long*)(ws + 147849216); // 128KB (0xAA poison != any tag)

    k_f2b<<<(G4 * EMB / 4 + 255) / 256, 256, 0, stream>>>(W_ih, Wihb, G4 * EMB);
    k_f2b<<<(NL * HID / 4 + 255) / 256, 256, 0, stream>>>(W_out, Woutb, NL * HID);
    k_f2b<<<(G4 * HID / 4 + 255) / 256, 256, 0, stream>>>(W_hh, Whhb, G4 * HID);
    k_emb<<<SEQ, 256, 0, stream>>>(ids, W_emb, embb);

    dim3 g1(SEQ / BM, G4 / BN);
    k_gemm_bt<<<g1, 256, 0, stream>>>(embb, Wihb, b_ih, b_hh, nullptr, xg, SEQ, G4, EMB);

    hipFuncSetAttribute((const void*)k_lstm, hipFuncAttributeMaxDynamicSharedMemorySize, LSTM_LDS);
    k_lstm<<<128, 1024, LSTM_LDS, stream>>>(Whhb, xg, h0, c0, hsb, out + (size_t)SEQ * NL, hcomm);

    dim3 g2(SEQ / BM, NL / BN);
    k_gemm_bt<<<g2, 256, 0, stream>>>(hsb, Woutb, b_out, nullptr, logit, nullptr, SEQ, NL, HID);

    k_softmax<<<SEQ / 4, 256, 0, stream>>>(logit, out);
}